// Round 2
// 343.334 us; speedup vs baseline: 1.0101x; 1.0101x over previous
//
#include <hip/hip_runtime.h>
#include <cstdint>
#include <cstddef>

// N=4, L=2048, E=1024, H=16, D=64.  Token rows M = N*L = 8192.
// Pipeline: cvt fp32->bf16, fused QKV projection GEMM (one 1536-block
// launch, BK=64), no-max flash attention (in-register P via swapped QK^T +
// permlane swaps, double-buffered K/V), output GEMM (fp32 out, BK=64).

typedef __bf16 bf16x8 __attribute__((ext_vector_type(8)));
typedef __bf16 bf16x4 __attribute__((ext_vector_type(4)));
typedef __bf16 bf16x2 __attribute__((ext_vector_type(2)));
typedef float f32x4 __attribute__((ext_vector_type(4)));
typedef float f32x2 __attribute__((ext_vector_type(2)));
typedef unsigned int uint2v __attribute__((ext_vector_type(2)));
typedef unsigned int uint4v __attribute__((ext_vector_type(4)));

#define LOG2E_OVER_SQRTD 0.18033688011112042f  // log2(e)/8, folded into q

__device__ __forceinline__ unsigned short f2bf(float f) {
  unsigned int u = __builtin_bit_cast(unsigned int, f);
  u = (u + 0x7fffu + ((u >> 16) & 1u)) >> 16;  // RNE
  return (unsigned short)u;
}

__device__ __forceinline__ unsigned int pk2(float a, float b) {
  f32x2 t = {a, b};
  bf16x2 h = __builtin_convertvector(t, bf16x2);  // v_cvt_pk_bf16_f32 (RNE)
  return __builtin_bit_cast(unsigned int, h);
}

// async 16B global->LDS
__device__ __forceinline__ void gl2lds16(const void* g, void* l) {
  __builtin_amdgcn_global_load_lds(
      (__attribute__((address_space(1))) unsigned int*)g,
      (__attribute__((address_space(3))) unsigned int*)l, 16, 0, 0);
}

// ---------------------------------------------------------------- cvt kernel
struct CvtArgs {
  const float* src[4];
  unsigned short* dst[4];
};
__global__ __launch_bounds__(256) void cvt_multi_k(CvtArgs a) {
  const float* s = a.src[blockIdx.y];
  unsigned short* d = a.dst[blockIdx.y];
  size_t i = ((size_t)blockIdx.x * 256 + threadIdx.x) * 4;
  float4 v = *(const float4*)(s + i);
  ushort4 o;
  o.x = f2bf(v.x); o.y = f2bf(v.y); o.z = f2bf(v.z); o.w = f2bf(v.w);
  *(ushort4*)(d + i) = o;
}

// ---------------------------------------------------------------- GEMM
// C[M][N] = A[M][1024] @ Bt[N][1024]^T, bf16 in, fp32 acc.  128x128 tile,
// BK=64 (16 K-iters), 4 waves each 64x64.  Multi-GEMM: blockIdx.x>>9 picks
// the descriptor (512 blocks per GEMM).
struct GemmDesc {
  const unsigned short* A;
  const unsigned short* Bt;
  const float* bias;
  void* C;
  int N;          // C column count / row stride
  int nbx_shift;  // log2(N/128)
  float scale;
  int bias_row;   // bias indexed by row instead of col
  int permc;      // store cols permuted: col' = 4*(col&15) + ((col>>4)&3)
};
struct GemmPack3 {
  GemmDesc g[3];
};

template <bool OUT_F32>
__global__ __launch_bounds__(256, 2) void gemm_multi_k(GemmPack3 p) {
  __shared__ __attribute__((aligned(16))) unsigned short As[128 * 64];
  __shared__ __attribute__((aligned(16))) unsigned short Bs[128 * 64];
  const GemmDesc d = p.g[blockIdx.x >> 9];
  const int t = blockIdx.x & 511;
  const int bx = t & ((1 << d.nbx_shift) - 1);
  const int by = t >> d.nbx_shift;

  const int tid = threadIdx.x;
  const int lane = tid & 63, wave = tid >> 6;
  const int lr = lane & 15, lg = lane >> 4;
  const int rowBase = by * 128;
  const int colBase = bx * 128;
  const int wm = (wave & 1) * 64, wn = (wave >> 1) * 64;

  f32x4 acc[4][4] = {};

  // staging: 4 slots/thread/matrix; slot s -> row=s>>3, seg t=s&7,
  // global chunk c = t ^ (row&7)  (reader swizzle matches)
  const unsigned short* gA[4];
  const unsigned short* gB[4];
  unsigned short* lA[4];
  unsigned short* lB[4];
#pragma unroll
  for (int i = 0; i < 4; ++i) {
    int s = tid + i * 256;
    int row = s >> 3;
    int c = (s & 7) ^ (row & 7);
    gA[i] = d.A + (size_t)(rowBase + row) * 1024 + c * 8;
    gB[i] = d.Bt + (size_t)(colBase + row) * 1024 + c * 8;
    lA[i] = &As[s * 8];
    lB[i] = &Bs[s * 8];
  }

  for (int kt = 0; kt < 16; ++kt) {
    const int ko = kt * 64;
#pragma unroll
    for (int i = 0; i < 4; ++i) {
      gl2lds16(gA[i] + ko, lA[i]);
      gl2lds16(gB[i] + ko, lB[i]);
    }
    __syncthreads();  // drains vmcnt before barrier (m97 structure)

#pragma unroll
    for (int ks = 0; ks < 2; ++ks) {
      bf16x8 af[4], bfr[4];
#pragma unroll
      for (int mt = 0; mt < 4; ++mt) {
        int row = wm + mt * 16 + lr;
        int c = (ks * 4 + lg) ^ (row & 7);
        af[mt] = *(const bf16x8*)&As[row * 64 + c * 8];
      }
#pragma unroll
      for (int nt = 0; nt < 4; ++nt) {
        int row = wn + nt * 16 + lr;
        int c = (ks * 4 + lg) ^ (row & 7);
        bfr[nt] = *(const bf16x8*)&Bs[row * 64 + c * 8];
      }
#pragma unroll
      for (int mt = 0; mt < 4; ++mt)
#pragma unroll
        for (int nt = 0; nt < 4; ++nt)
          acc[mt][nt] = __builtin_amdgcn_mfma_f32_16x16x32_bf16(
              af[mt], bfr[nt], acc[mt][nt], 0, 0, 0);
    }
    __syncthreads();  // waves done reading before restage
  }

  // epilogue: C-layout col=lane&15, row=(lane>>4)*4+reg
#pragma unroll
  for (int mt = 0; mt < 4; ++mt)
#pragma unroll
    for (int nt = 0; nt < 4; ++nt) {
      int col = colBase + wn + nt * 16 + lr;
      int colStore = d.permc ? (colBase + wn + lr * 4 + nt) : col;
      float bcol = d.bias_row ? 0.f : d.bias[col];
#pragma unroll
      for (int r = 0; r < 4; ++r) {
        int row = rowBase + wm + mt * 16 + lg * 4 + r;
        float b = d.bias_row ? d.bias[row] : bcol;
        float val = (acc[mt][nt][r] + b) * d.scale;
        size_t idx = (size_t)row * (size_t)d.N + (size_t)colStore;
        if (OUT_F32)
          ((float*)d.C)[idx] = val;
        else
          ((unsigned short*)d.C)[idx] = f2bf(val);
      }
    }
}

// ---------------------------------------------------------------- attention
// One block per (n, h, 128-row q-tile).  4 waves x 32 q-rows.  KT=64.
// Swapped QK^T: s_acc = mfma(K_frag, Q_frag) = S^T (rows=key, cols=q), so
// each lane owns P^T[k][q] for its q-column.  P never touches LDS: bf16
// pack (cvt_pk) + permlane32_swap + permlane16_swap rearrange P^T into the
// PV A-operand fragments in-register (NATURAL key order -- V^T must be
// stored unpermuted!).  K/V double-buffered in LDS, one barrier per k-tile,
// prefetch issued before compute (2-phase recipe).
// qb pre-scaled by log2(e)/sqrt(D); no-max softmax: p=exp2(s), row-sum
// deferred to epilogue (2 scalars/lane + shfl_xor 16/32 reduce).
__global__ __launch_bounds__(256, 4) void attn_k(
    const unsigned short* __restrict__ qb,   // [8192][1024]
    const unsigned short* __restrict__ kb,   // [8192][1024]
    const unsigned short* __restrict__ vtb,  // [1024][8192] natural key order
    unsigned short* __restrict__ aob) {      // [8192][1024]
  __shared__ __attribute__((aligned(16))) unsigned short Ks[2 * 64 * 64];
  __shared__ __attribute__((aligned(16))) unsigned short Vts[2 * 64 * 64];

  const int tid = threadIdx.x;
  const int lane = tid & 63, wave = tid >> 6;
  const int lr = lane & 15, lg = lane >> 4;

  const int bid = blockIdx.x;
  const int qt = bid & 15;
  const int nh = bid >> 4;
  const int h = nh & 15, n = nh >> 4;
  const int q0 = qt * 128;

  // ---- stage Q tile (128x64 = 16KB) overlaying both K buffers
#pragma unroll
  for (int i = 0; i < 4; ++i) {
    int s = i * 256 + tid;
    int row = s >> 3;
    int c = (s & 7) ^ (row & 7);
    gl2lds16(qb + (((size_t)n * 2048 + q0 + row) << 10) + h * 64 + c * 8,
             &Ks[s * 8]);
  }
  __syncthreads();

  bf16x8 aq[2][2];
#pragma unroll
  for (int mt = 0; mt < 2; ++mt)
#pragma unroll
    for (int ks = 0; ks < 2; ++ks) {
      int row = wave * 32 + mt * 16 + lr;
      int c = (ks * 4 + lg) ^ (row & 7);
      aq[mt][ks] = *(const bf16x8*)&Ks[row * 64 + c * 8];
    }
  __syncthreads();  // Q reads done; Ks becomes K double-buffer

  // staging addresses fixed per thread; advance by one tile per iteration
  const unsigned short* kg[2];
  const unsigned short* vg[2];
  int ldo[2];
#pragma unroll
  for (int i = 0; i < 2; ++i) {
    int s = i * 256 + tid;
    int row = s >> 3;
    int c = (s & 7) ^ (row & 7);
    kg[i] = kb + (((size_t)n * 2048 + row) << 10) + h * 64 + c * 8;
    vg[i] = vtb + (((size_t)(h * 64 + row)) << 13) + (size_t)n * 2048 + c * 8;
    ldo[i] = s * 8;
  }
  // stage k-tile 0 into buffer 0
#pragma unroll
  for (int i = 0; i < 2; ++i) {
    gl2lds16(kg[i], &Ks[ldo[i]]);
    gl2lds16(vg[i], &Vts[ldo[i]]);
    kg[i] += 64 * 1024;
    vg[i] += 64;
  }

  f32x4 o_acc[2][4] = {};
  float lsum[2] = {};

  for (int kt = 0; kt < 32; ++kt) {
    const int cb = (kt & 1) * 4096;  // current buffer base (shorts)
    const int nb = 4096 - cb;        // next buffer base
    __syncthreads();  // buf[cur] staged; prior reads of buf[next] complete

    if (kt < 31) {  // prefetch next tile before compute (loads overlap MFMA)
#pragma unroll
      for (int i = 0; i < 2; ++i) {
        gl2lds16(kg[i], &Ks[nb + ldo[i]]);
        gl2lds16(vg[i], &Vts[nb + ldo[i]]);
        kg[i] += 64 * 1024;
        vg[i] += 64;
      }
    }

    // swapped QK^T: s_acc[mt][nt] = S^T tile (row=key nt*16+lg*4+r, col=q)
    f32x4 s_acc[2][4] = {};
#pragma unroll
    for (int ks = 0; ks < 2; ++ks)
#pragma unroll
      for (int nt = 0; nt < 4; ++nt) {
        int row = nt * 16 + lr;
        int c = (ks * 4 + lg) ^ (row & 7);
        bf16x8 kf = *(const bf16x8*)&Ks[cb + row * 64 + c * 8];
#pragma unroll
        for (int mt = 0; mt < 2; ++mt)
          s_acc[mt][nt] = __builtin_amdgcn_mfma_f32_16x16x32_bf16(
              kf, aq[mt][ks], s_acc[mt][nt], 0, 0, 0);
      }

    // no-max softmax + in-register P->A-fragment rearrangement.
    // lane (g'=lg, q=lr+mt*16) holds P^T[k=16nt+4g'+r][q].  PV A-frag needs
    // P[q][k=8g..8g+7] in lane group g (natural key order).
    // pk[nt][w]=pack(p[2w],p[2w+1]);
    // permlane32_swap(pk[ntA][w],pk[ntB][w]) -> permlane16_swap gives
    // A-words (w0,w2) and (w1,w3).
    bf16x8 ap[2][2];
#pragma unroll
    for (int mt = 0; mt < 2; ++mt) {
#pragma unroll
      for (int ks = 0; ks < 2; ++ks) {
        float pe[2][4];
#pragma unroll
        for (int half = 0; half < 2; ++half) {
          int nt = ks * 2 + half;
#pragma unroll
          for (int r = 0; r < 4; ++r)
            pe[half][r] = __builtin_amdgcn_exp2f(s_acc[mt][nt][r]);
          lsum[mt] += (pe[half][0] + pe[half][1]) + (pe[half][2] + pe[half][3]);
        }
        unsigned int x00 = pk2(pe[0][0], pe[0][1]);
        unsigned int x01 = pk2(pe[0][2], pe[0][3]);
        unsigned int x10 = pk2(pe[1][0], pe[1][1]);
        unsigned int x11 = pk2(pe[1][2], pe[1][3]);
        uint2v s0 = __builtin_amdgcn_permlane32_swap(x00, x10, false, false);
        uint2v t0 = __builtin_amdgcn_permlane16_swap(s0[0], s0[1], false, false);
        uint2v s1 = __builtin_amdgcn_permlane32_swap(x01, x11, false, false);
        uint2v t1 = __builtin_amdgcn_permlane16_swap(s1[0], s1[1], false, false);
        uint4v u;
        u[0] = t0[0];  // k 8g+0,1
        u[1] = t1[0];  // k 8g+2,3
        u[2] = t0[1];  // k 8g+4,5
        u[3] = t1[1];  // k 8g+6,7
        ap[mt][ks] = __builtin_bit_cast(bf16x8, u);
      }
    }

    // PV: O[q][d] += P * V
#pragma unroll
    for (int ks = 0; ks < 2; ++ks) {
      bf16x8 bv[4];
#pragma unroll
      for (int nt = 0; nt < 4; ++nt) {
        int row = nt * 16 + lr;
        int c = (ks * 4 + lg) ^ (row & 7);
        bv[nt] = *(const bf16x8*)&Vts[cb + row * 64 + c * 8];
      }
#pragma unroll
      for (int mt = 0; mt < 2; ++mt)
#pragma unroll
        for (int nt = 0; nt < 4; ++nt)
          o_acc[mt][nt] = __builtin_amdgcn_mfma_f32_16x16x32_bf16(
              ap[mt][ks], bv[nt], o_acc[mt][nt], 0, 0, 0);
    }
  }

  // epilogue: O C-layout col=d=lane&15, row=q=(lane>>4)*4+r.
  // lsum[mt] is the partial row-sum for q-col (lane&15); reduce across the
  // 4 lane-groups, then fetch the sum for this lane's O-row via shfl.
#pragma unroll
  for (int mt = 0; mt < 2; ++mt) {
    float l = lsum[mt];
    l += __shfl_xor(l, 16);
    l += __shfl_xor(l, 32);
#pragma unroll
    for (int r = 0; r < 4; ++r) {
      float lv = __shfl(l, lg * 4 + r);  // lane (lg*4+r) owns q-col lg*4+r
      float inv = 1.0f / lv;
      int row_l = q0 + wave * 32 + mt * 16 + lg * 4 + r;
      size_t base = (((size_t)n * 2048 + row_l) << 10) + h * 64;
#pragma unroll
      for (int nt = 0; nt < 4; ++nt)
        aob[base + nt * 16 + lr] = f2bf(o_acc[mt][nt][r] * inv);
    }
  }
}

// ---------------------------------------------------------------- launch
extern "C" void kernel_launch(void* const* d_in, const int* in_sizes, int n_in,
                              void* d_out, int out_size, void* d_ws,
                              size_t ws_size, hipStream_t stream) {
  const float* Q = (const float*)d_in[0];
  const float* K = (const float*)d_in[1];
  const float* V = (const float*)d_in[2];
  const float* Wq = (const float*)d_in[3];
  const float* bq = (const float*)d_in[4];
  const float* Wk = (const float*)d_in[5];
  const float* bk = (const float*)d_in[6];
  const float* Wv = (const float*)d_in[7];
  const float* bv = (const float*)d_in[8];
  const float* Wo = (const float*)d_in[9];
  const float* bo = (const float*)d_in[10];

  const size_t S = (size_t)8192 * 1024;
  const size_t W = (size_t)1024 * 1024;
  unsigned short* ws = (unsigned short*)d_ws;
  unsigned short* Qbf = ws;  // dead after q-proj; reused as attention output
  unsigned short* Kbf = ws + S;
  unsigned short* Vbf = ws + 2 * S;
  unsigned short* qbuf = ws + 3 * S;
  unsigned short* kbuf = ws + 4 * S;
  unsigned short* vtbuf = ws + 5 * S;
  unsigned short* Wqb = ws + 6 * S;
  unsigned short* Wkb = Wqb + W;
  unsigned short* Wvb = Wqb + 2 * W;
  unsigned short* Wob = Wqb + 3 * W;
  unsigned short* aob = Qbf;

  CvtArgs cx;
  cx.src[0] = Q; cx.dst[0] = Qbf;
  cx.src[1] = K; cx.dst[1] = Kbf;
  cx.src[2] = V; cx.dst[2] = Vbf;
  cx.src[3] = Q; cx.dst[3] = Qbf;  // unused slot
  cvt_multi_k<<<dim3(8192, 3), 256, 0, stream>>>(cx);

  CvtArgs cw;
  cw.src[0] = Wq; cw.dst[0] = Wqb;
  cw.src[1] = Wk; cw.dst[1] = Wkb;
  cw.src[2] = Wv; cw.dst[2] = Wvb;
  cw.src[3] = Wo; cw.dst[3] = Wob;
  cvt_multi_k<<<dim3(1024, 4), 256, 0, stream>>>(cw);

  // fused QKV projections: g0: q = (Qbf Wq^T + bq)*log2e/8  [8192x1024]
  //                        g1: k =  Kbf Wk^T + bk           [8192x1024]
  //                        g2: v^T = Wvb Vbf^T + bv (natural order) [1024x8192]
  GemmPack3 pp;
  pp.g[0] = {Qbf, Wqb, bq, qbuf, 1024, 3, LOG2E_OVER_SQRTD, 0, 0};
  pp.g[1] = {Kbf, Wkb, bk, kbuf, 1024, 3, 1.0f, 0, 0};
  pp.g[2] = {Wvb, Vbf, bv, vtbuf, 8192, 6, 1.0f, 1, 0};
  gemm_multi_k<false><<<1536, 256, 0, stream>>>(pp);

  attn_k<<<1024, 256, 0, stream>>>(qbuf, kbuf, vtbuf, aob);

  // out = AO Wo^T + bo  (fp32)
  GemmPack3 po;
  po.g[0] = {aob, Wob, bo, d_out, 1024, 3, 1.0f, 0, 0};
  po.g[1] = po.g[0];
  po.g[2] = po.g[0];
  gemm_multi_k<true><<<512, 256, 0, stream>>>(po);
}

// Round 3
// 341.039 us; speedup vs baseline: 1.0169x; 1.0067x over previous
//
#include <hip/hip_runtime.h>
#include <cstdint>
#include <cstddef>

// N=4, L=2048, E=1024, H=16, D=64.  Token rows M = N*L = 8192.
// Pipeline: cvt fp32->bf16, fused QKV projection GEMM (one 1536-block
// launch, BK=64), no-max flash attention (in-register P via swapped QK^T +
// permlane swaps, double-buffered K/V, XCD-local head placement, row-sum
// via ones-MFMA), output GEMM (fp32 out, BK=64).

typedef __bf16 bf16x8 __attribute__((ext_vector_type(8)));
typedef __bf16 bf16x4 __attribute__((ext_vector_type(4)));
typedef __bf16 bf16x2 __attribute__((ext_vector_type(2)));
typedef float f32x4 __attribute__((ext_vector_type(4)));
typedef float f32x2 __attribute__((ext_vector_type(2)));
typedef unsigned int uint2v __attribute__((ext_vector_type(2)));
typedef unsigned int uint4v __attribute__((ext_vector_type(4)));

#define LOG2E_OVER_SQRTD 0.18033688011112042f  // log2(e)/8, folded into q

__device__ __forceinline__ unsigned short f2bf(float f) {
  unsigned int u = __builtin_bit_cast(unsigned int, f);
  u = (u + 0x7fffu + ((u >> 16) & 1u)) >> 16;  // RNE
  return (unsigned short)u;
}

__device__ __forceinline__ unsigned int pk2(float a, float b) {
  f32x2 t = {a, b};
  bf16x2 h = __builtin_convertvector(t, bf16x2);  // v_cvt_pk_bf16_f32 (RNE)
  return __builtin_bit_cast(unsigned int, h);
}

// async 16B global->LDS
__device__ __forceinline__ void gl2lds16(const void* g, void* l) {
  __builtin_amdgcn_global_load_lds(
      (__attribute__((address_space(1))) unsigned int*)g,
      (__attribute__((address_space(3))) unsigned int*)l, 16, 0, 0);
}

// ---------------------------------------------------------------- cvt kernel
struct CvtArgs {
  const float* src[4];
  unsigned short* dst[4];
};
__global__ __launch_bounds__(256) void cvt_multi_k(CvtArgs a) {
  const float* s = a.src[blockIdx.y];
  unsigned short* d = a.dst[blockIdx.y];
  size_t i = ((size_t)blockIdx.x * 256 + threadIdx.x) * 4;
  float4 v = *(const float4*)(s + i);
  ushort4 o;
  o.x = f2bf(v.x); o.y = f2bf(v.y); o.z = f2bf(v.z); o.w = f2bf(v.w);
  *(ushort4*)(d + i) = o;
}

// ---------------------------------------------------------------- GEMM
// C[M][N] = A[M][1024] @ Bt[N][1024]^T, bf16 in, fp32 acc.  128x128 tile,
// BK=64 (16 K-iters), 4 waves each 64x64.  Multi-GEMM: blockIdx.x>>9 picks
// the descriptor (512 blocks per GEMM).
struct GemmDesc {
  const unsigned short* A;
  const unsigned short* Bt;
  const float* bias;
  void* C;
  int N;          // C column count / row stride
  int nbx_shift;  // log2(N/128)
  float scale;
  int bias_row;   // bias indexed by row instead of col
  int permc;      // store cols permuted: col' = 4*(col&15) + ((col>>4)&3)
};
struct GemmPack3 {
  GemmDesc g[3];
};

template <bool OUT_F32>
__global__ __launch_bounds__(256, 2) void gemm_multi_k(GemmPack3 p) {
  __shared__ __attribute__((aligned(16))) unsigned short As[128 * 64];
  __shared__ __attribute__((aligned(16))) unsigned short Bs[128 * 64];
  const GemmDesc d = p.g[blockIdx.x >> 9];
  const int t = blockIdx.x & 511;
  const int bx = t & ((1 << d.nbx_shift) - 1);
  const int by = t >> d.nbx_shift;

  const int tid = threadIdx.x;
  const int lane = tid & 63, wave = tid >> 6;
  const int lr = lane & 15, lg = lane >> 4;
  const int rowBase = by * 128;
  const int colBase = bx * 128;
  const int wm = (wave & 1) * 64, wn = (wave >> 1) * 64;

  f32x4 acc[4][4] = {};

  // staging: 4 slots/thread/matrix; slot s -> row=s>>3, seg t=s&7,
  // global chunk c = t ^ (row&7)  (reader swizzle matches)
  const unsigned short* gA[4];
  const unsigned short* gB[4];
  unsigned short* lA[4];
  unsigned short* lB[4];
#pragma unroll
  for (int i = 0; i < 4; ++i) {
    int s = tid + i * 256;
    int row = s >> 3;
    int c = (s & 7) ^ (row & 7);
    gA[i] = d.A + (size_t)(rowBase + row) * 1024 + c * 8;
    gB[i] = d.Bt + (size_t)(colBase + row) * 1024 + c * 8;
    lA[i] = &As[s * 8];
    lB[i] = &Bs[s * 8];
  }

  for (int kt = 0; kt < 16; ++kt) {
    const int ko = kt * 64;
#pragma unroll
    for (int i = 0; i < 4; ++i) {
      gl2lds16(gA[i] + ko, lA[i]);
      gl2lds16(gB[i] + ko, lB[i]);
    }
    __syncthreads();  // drains vmcnt before barrier (m97 structure)

#pragma unroll
    for (int ks = 0; ks < 2; ++ks) {
      bf16x8 af[4], bfr[4];
#pragma unroll
      for (int mt = 0; mt < 4; ++mt) {
        int row = wm + mt * 16 + lr;
        int c = (ks * 4 + lg) ^ (row & 7);
        af[mt] = *(const bf16x8*)&As[row * 64 + c * 8];
      }
#pragma unroll
      for (int nt = 0; nt < 4; ++nt) {
        int row = wn + nt * 16 + lr;
        int c = (ks * 4 + lg) ^ (row & 7);
        bfr[nt] = *(const bf16x8*)&Bs[row * 64 + c * 8];
      }
#pragma unroll
      for (int mt = 0; mt < 4; ++mt)
#pragma unroll
        for (int nt = 0; nt < 4; ++nt)
          acc[mt][nt] = __builtin_amdgcn_mfma_f32_16x16x32_bf16(
              af[mt], bfr[nt], acc[mt][nt], 0, 0, 0);
    }
    __syncthreads();  // waves done reading before restage
  }

  // epilogue: C-layout col=lane&15, row=(lane>>4)*4+reg
#pragma unroll
  for (int mt = 0; mt < 4; ++mt)
#pragma unroll
    for (int nt = 0; nt < 4; ++nt) {
      int col = colBase + wn + nt * 16 + lr;
      int colStore = d.permc ? (colBase + wn + lr * 4 + nt) : col;
      float bcol = d.bias_row ? 0.f : d.bias[col];
#pragma unroll
      for (int r = 0; r < 4; ++r) {
        int row = rowBase + wm + mt * 16 + lg * 4 + r;
        float b = d.bias_row ? d.bias[row] : bcol;
        float val = (acc[mt][nt][r] + b) * d.scale;
        size_t idx = (size_t)row * (size_t)d.N + (size_t)colStore;
        if (OUT_F32)
          ((float*)d.C)[idx] = val;
        else
          ((unsigned short*)d.C)[idx] = f2bf(val);
      }
    }
}

// ---------------------------------------------------------------- attention
// One block per (n, h, 128-row q-tile).  4 waves x 32 q-rows.  KT=64.
// XCD-local placement: blocks are remapped so all 16 q-tiles of one (n,h)
// land on the SAME XCD (dispatch round-robins XCD = bid%8), making the
// shared K/V panels (512 KB/head) L2-resident instead of L3-streamed.
// Swapped QK^T: s_acc = mfma(K_frag, Q_frag) = S^T (rows=key, cols=q), so
// each lane owns P^T[k][q] for its q-column.  P never touches LDS: bf16
// pack (cvt_pk) + permlane32_swap + permlane16_swap rearrange P^T into the
// PV A-operand fragments in-register (natural key order; V^T unpermuted).
// Row-sum via ones-MFMA: o_sum = mfma(ap, ones) lands per-O-row in the
// same C layout as o_acc -- no VALU adds, no epilogue shuffle.
// K/V double-buffered in LDS, one barrier per k-tile, prefetch issued
// before compute.  qb pre-scaled by log2(e)/sqrt(D); no-max softmax.
__global__ __launch_bounds__(256, 4) void attn_k(
    const unsigned short* __restrict__ qb,   // [8192][1024]
    const unsigned short* __restrict__ kb,   // [8192][1024]
    const unsigned short* __restrict__ vtb,  // [1024][8192] natural key order
    unsigned short* __restrict__ aob) {      // [8192][1024]
  __shared__ __attribute__((aligned(16))) unsigned short Ks[2 * 64 * 64];
  __shared__ __attribute__((aligned(16))) unsigned short Vts[2 * 64 * 64];

  const int tid = threadIdx.x;
  const int lane = tid & 63, wave = tid >> 6;
  const int lr = lane & 15, lg = lane >> 4;

  // XCD-local swizzle: xcd = bid&7 (dispatch round-robin), 16 q-tiles of
  // each nh stay on one XCD.  Bijective: nh = (idx>>4)*8 + xcd in [0,64).
  const int bid = blockIdx.x;
  const int xcd = bid & 7;
  const int idx = bid >> 3;
  const int qt = idx & 15;
  const int nh = (idx >> 4) * 8 + xcd;
  const int h = nh & 15, n = nh >> 4;
  const int q0 = qt * 128;

  // ---- stage Q tile (128x64 = 16KB) overlaying both K buffers
#pragma unroll
  for (int i = 0; i < 4; ++i) {
    int s = i * 256 + tid;
    int row = s >> 3;
    int c = (s & 7) ^ (row & 7);
    gl2lds16(qb + (((size_t)n * 2048 + q0 + row) << 10) + h * 64 + c * 8,
             &Ks[s * 8]);
  }
  __syncthreads();

  bf16x8 aq[2][2];
#pragma unroll
  for (int mt = 0; mt < 2; ++mt)
#pragma unroll
    for (int ks = 0; ks < 2; ++ks) {
      int row = wave * 32 + mt * 16 + lr;
      int c = (ks * 4 + lg) ^ (row & 7);
      aq[mt][ks] = *(const bf16x8*)&Ks[row * 64 + c * 8];
    }
  __syncthreads();  // Q reads done; Ks becomes K double-buffer

  // staging addresses fixed per thread; advance by one tile per iteration
  const unsigned short* kg[2];
  const unsigned short* vg[2];
  int ldo[2];
#pragma unroll
  for (int i = 0; i < 2; ++i) {
    int s = i * 256 + tid;
    int row = s >> 3;
    int c = (s & 7) ^ (row & 7);
    kg[i] = kb + (((size_t)n * 2048 + row) << 10) + h * 64 + c * 8;
    vg[i] = vtb + (((size_t)(h * 64 + row)) << 13) + (size_t)n * 2048 + c * 8;
    ldo[i] = s * 8;
  }
  // stage k-tile 0 into buffer 0
#pragma unroll
  for (int i = 0; i < 2; ++i) {
    gl2lds16(kg[i], &Ks[ldo[i]]);
    gl2lds16(vg[i], &Vts[ldo[i]]);
    kg[i] += 64 * 1024;
    vg[i] += 64;
  }

  bf16x8 ones;
#pragma unroll
  for (int i = 0; i < 8; ++i) ones[i] = (__bf16)1.0f;

  f32x4 o_acc[2][4] = {};
  f32x4 o_sum[2] = {};

  for (int kt = 0; kt < 32; ++kt) {
    const int cb = (kt & 1) * 4096;  // current buffer base (shorts)
    const int nb = 4096 - cb;        // next buffer base
    __syncthreads();  // buf[cur] staged; prior reads of buf[next] complete

    if (kt < 31) {  // prefetch next tile before compute (loads overlap MFMA)
#pragma unroll
      for (int i = 0; i < 2; ++i) {
        gl2lds16(kg[i], &Ks[nb + ldo[i]]);
        gl2lds16(vg[i], &Vts[nb + ldo[i]]);
        kg[i] += 64 * 1024;
        vg[i] += 64;
      }
    }

    // swapped QK^T: s_acc[mt][nt] = S^T tile (row=key nt*16+lg*4+r, col=q)
    f32x4 s_acc[2][4] = {};
#pragma unroll
    for (int ks = 0; ks < 2; ++ks)
#pragma unroll
      for (int nt = 0; nt < 4; ++nt) {
        int row = nt * 16 + lr;
        int c = (ks * 4 + lg) ^ (row & 7);
        bf16x8 kf = *(const bf16x8*)&Ks[cb + row * 64 + c * 8];
#pragma unroll
        for (int mt = 0; mt < 2; ++mt)
          s_acc[mt][nt] = __builtin_amdgcn_mfma_f32_16x16x32_bf16(
              kf, aq[mt][ks], s_acc[mt][nt], 0, 0, 0);
      }

    // no-max softmax + in-register P->A-fragment rearrangement.
    // lane (g'=lg, q=lr+mt*16) holds P^T[k=16nt+4g'+r][q].  PV A-frag needs
    // P[q][k=8g..8g+7] in lane group g (natural key order).
    // pk[nt][w]=pack(p[2w],p[2w+1]);
    // permlane32_swap(pk[ntA][w],pk[ntB][w]) -> permlane16_swap gives
    // A-words (w0,w2) and (w1,w3).
    bf16x8 ap[2][2];
#pragma unroll
    for (int mt = 0; mt < 2; ++mt) {
#pragma unroll
      for (int ks = 0; ks < 2; ++ks) {
        float pe[2][4];
#pragma unroll
        for (int half = 0; half < 2; ++half) {
          int nt = ks * 2 + half;
#pragma unroll
          for (int r = 0; r < 4; ++r)
            pe[half][r] = __builtin_amdgcn_exp2f(s_acc[mt][nt][r]);
        }
        unsigned int x00 = pk2(pe[0][0], pe[0][1]);
        unsigned int x01 = pk2(pe[0][2], pe[0][3]);
        unsigned int x10 = pk2(pe[1][0], pe[1][1]);
        unsigned int x11 = pk2(pe[1][2], pe[1][3]);
        uint2v s0 = __builtin_amdgcn_permlane32_swap(x00, x10, false, false);
        uint2v t0 = __builtin_amdgcn_permlane16_swap(s0[0], s0[1], false, false);
        uint2v s1 = __builtin_amdgcn_permlane32_swap(x01, x11, false, false);
        uint2v t1 = __builtin_amdgcn_permlane16_swap(s1[0], s1[1], false, false);
        uint4v u;
        u[0] = t0[0];  // k 8g+0,1
        u[1] = t1[0];  // k 8g+2,3
        u[2] = t0[1];  // k 8g+4,5
        u[3] = t1[1];  // k 8g+6,7
        ap[mt][ks] = __builtin_bit_cast(bf16x8, u);
      }
    }

    // row-sum via ones-MFMA: every C column identical = sum_k P[q][k];
    // lands row=q=(lg*4+r) like o_acc -> no epilogue shuffle needed.
#pragma unroll
    for (int mt = 0; mt < 2; ++mt)
#pragma unroll
      for (int ks = 0; ks < 2; ++ks)
        o_sum[mt] = __builtin_amdgcn_mfma_f32_16x16x32_bf16(
            ap[mt][ks], ones, o_sum[mt], 0, 0, 0);

    // PV: O[q][d] += P * V
#pragma unroll
    for (int ks = 0; ks < 2; ++ks) {
      bf16x8 bv[4];
#pragma unroll
      for (int nt = 0; nt < 4; ++nt) {
        int row = nt * 16 + lr;
        int c = (ks * 4 + lg) ^ (row & 7);
        bv[nt] = *(const bf16x8*)&Vts[cb + row * 64 + c * 8];
      }
#pragma unroll
      for (int mt = 0; mt < 2; ++mt)
#pragma unroll
        for (int nt = 0; nt < 4; ++nt)
          o_acc[mt][nt] = __builtin_amdgcn_mfma_f32_16x16x32_bf16(
              ap[mt][ks], bv[nt], o_acc[mt][nt], 0, 0, 0);
    }
  }

  // epilogue: O C-layout col=d=lane&15, row=q=(lane>>4)*4+r.
  // o_sum[mt][r] is the full row-sum for this lane's O-row already.
#pragma unroll
  for (int mt = 0; mt < 2; ++mt) {
#pragma unroll
    for (int r = 0; r < 4; ++r) {
      float inv = 1.0f / o_sum[mt][r];
      int row_l = q0 + wave * 32 + mt * 16 + lg * 4 + r;
      size_t base = (((size_t)n * 2048 + row_l) << 10) + h * 64;
#pragma unroll
      for (int nt = 0; nt < 4; ++nt)
        aob[base + nt * 16 + lr] = f2bf(o_acc[mt][nt][r] * inv);
    }
  }
}

// ---------------------------------------------------------------- launch
extern "C" void kernel_launch(void* const* d_in, const int* in_sizes, int n_in,
                              void* d_out, int out_size, void* d_ws,
                              size_t ws_size, hipStream_t stream) {
  const float* Q = (const float*)d_in[0];
  const float* K = (const float*)d_in[1];
  const float* V = (const float*)d_in[2];
  const float* Wq = (const float*)d_in[3];
  const float* bq = (const float*)d_in[4];
  const float* Wk = (const float*)d_in[5];
  const float* bk = (const float*)d_in[6];
  const float* Wv = (const float*)d_in[7];
  const float* bv = (const float*)d_in[8];
  const float* Wo = (const float*)d_in[9];
  const float* bo = (const float*)d_in[10];

  const size_t S = (size_t)8192 * 1024;
  const size_t W = (size_t)1024 * 1024;
  unsigned short* ws = (unsigned short*)d_ws;
  unsigned short* Qbf = ws;  // dead after q-proj; reused as attention output
  unsigned short* Kbf = ws + S;
  unsigned short* Vbf = ws + 2 * S;
  unsigned short* qbuf = ws + 3 * S;
  unsigned short* kbuf = ws + 4 * S;
  unsigned short* vtbuf = ws + 5 * S;
  unsigned short* Wqb = ws + 6 * S;
  unsigned short* Wkb = Wqb + W;
  unsigned short* Wvb = Wqb + 2 * W;
  unsigned short* Wob = Wqb + 3 * W;
  unsigned short* aob = Qbf;

  CvtArgs cx;
  cx.src[0] = Q; cx.dst[0] = Qbf;
  cx.src[1] = K; cx.dst[1] = Kbf;
  cx.src[2] = V; cx.dst[2] = Vbf;
  cx.src[3] = Q; cx.dst[3] = Qbf;  // unused slot
  cvt_multi_k<<<dim3(8192, 3), 256, 0, stream>>>(cx);

  CvtArgs cw;
  cw.src[0] = Wq; cw.dst[0] = Wqb;
  cw.src[1] = Wk; cw.dst[1] = Wkb;
  cw.src[2] = Wv; cw.dst[2] = Wvb;
  cw.src[3] = Wo; cw.dst[3] = Wob;
  cvt_multi_k<<<dim3(1024, 4), 256, 0, stream>>>(cw);

  // fused QKV projections: g0: q = (Qbf Wq^T + bq)*log2e/8  [8192x1024]
  //                        g1: k =  Kbf Wk^T + bk           [8192x1024]
  //                        g2: v^T = Wvb Vbf^T + bv (natural order) [1024x8192]
  GemmPack3 pp;
  pp.g[0] = {Qbf, Wqb, bq, qbuf, 1024, 3, LOG2E_OVER_SQRTD, 0, 0};
  pp.g[1] = {Kbf, Wkb, bk, kbuf, 1024, 3, 1.0f, 0, 0};
  pp.g[2] = {Wvb, Vbf, bv, vtbuf, 8192, 6, 1.0f, 1, 0};
  gemm_multi_k<false><<<1536, 256, 0, stream>>>(pp);

  attn_k<<<1024, 256, 0, stream>>>(qbuf, kbuf, vtbuf, aob);

  // out = AO Wo^T + bo  (fp32)
  GemmPack3 po;
  po.g[0] = {aob, Wob, bo, d_out, 1024, 3, 1.0f, 0, 0};
  po.g[1] = po.g[0];
  po.g[2] = po.g[0];
  gemm_multi_k<true><<<512, 256, 0, stream>>>(po);
}

// Round 4
// 337.810 us; speedup vs baseline: 1.0267x; 1.0096x over previous
//
#include <hip/hip_runtime.h>
#include <cstdint>
#include <cstddef>

// N=4, L=2048, E=1024, H=16, D=64.  Token rows M = N*L = 8192.
// Pipeline: cvt fp32->bf16 (single merged launch), fused QKV projection
// GEMM (one 1536-block launch, BK=64), no-max flash attention (in-register
// P via swapped QK^T + permlane swaps, double-buffered K/V, XCD-local head
// placement, row-sum via ones-MFMA, zero-C QK^T, setprio), output GEMM.

typedef __bf16 bf16x8 __attribute__((ext_vector_type(8)));
typedef __bf16 bf16x4 __attribute__((ext_vector_type(4)));
typedef __bf16 bf16x2 __attribute__((ext_vector_type(2)));
typedef float f32x4 __attribute__((ext_vector_type(4)));
typedef float f32x2 __attribute__((ext_vector_type(2)));
typedef unsigned int uint2v __attribute__((ext_vector_type(2)));
typedef unsigned int uint4v __attribute__((ext_vector_type(4)));

#define LOG2E_OVER_SQRTD 0.18033688011112042f  // log2(e)/8, folded into q

__device__ __forceinline__ unsigned short f2bf(float f) {
  unsigned int u = __builtin_bit_cast(unsigned int, f);
  u = (u + 0x7fffu + ((u >> 16) & 1u)) >> 16;  // RNE
  return (unsigned short)u;
}

__device__ __forceinline__ unsigned int pk2(float a, float b) {
  f32x2 t = {a, b};
  bf16x2 h = __builtin_convertvector(t, bf16x2);  // v_cvt_pk_bf16_f32 (RNE)
  return __builtin_bit_cast(unsigned int, h);
}

// async 16B global->LDS
__device__ __forceinline__ void gl2lds16(const void* g, void* l) {
  __builtin_amdgcn_global_load_lds(
      (__attribute__((address_space(1))) unsigned int*)g,
      (__attribute__((address_space(3))) unsigned int*)l, 16, 0, 0);
}

// ---------------------------------------------------------------- cvt kernel
// Single launch: regions 0-2 = activations (8192 blocks each), 3-6 = weights
// (1024 blocks each).  Grid = 3*8192 + 4*1024 = 28672.
struct CvtArgs {
  const float* src[7];
  unsigned short* dst[7];
};
__global__ __launch_bounds__(256) void cvt_all_k(CvtArgs a) {
  int bid = blockIdx.x;
  int which, x;
  if (bid < 24576) {
    which = bid >> 13;
    x = bid & 8191;
  } else {
    int r = bid - 24576;
    which = 3 + (r >> 10);
    x = r & 1023;
  }
  const float* s = a.src[which];
  unsigned short* d = a.dst[which];
  size_t i = ((size_t)x * 256 + threadIdx.x) * 4;
  float4 v = *(const float4*)(s + i);
  ushort4 o;
  o.x = f2bf(v.x); o.y = f2bf(v.y); o.z = f2bf(v.z); o.w = f2bf(v.w);
  *(ushort4*)(d + i) = o;
}

// ---------------------------------------------------------------- GEMM
// C[M][N] = A[M][1024] @ Bt[N][1024]^T, bf16 in, fp32 acc.  128x128 tile,
// BK=64 (16 K-iters), 4 waves each 64x64.  Multi-GEMM: blockIdx.x>>9 picks
// the descriptor (512 blocks per GEMM).
struct GemmDesc {
  const unsigned short* A;
  const unsigned short* Bt;
  const float* bias;
  void* C;
  int N;          // C column count / row stride
  int nbx_shift;  // log2(N/128)
  float scale;
  int bias_row;   // bias indexed by row instead of col
  int permc;      // store cols permuted: col' = 4*(col&15) + ((col>>4)&3)
};
struct GemmPack3 {
  GemmDesc g[3];
};

template <bool OUT_F32>
__global__ __launch_bounds__(256, 2) void gemm_multi_k(GemmPack3 p) {
  __shared__ __attribute__((aligned(16))) unsigned short As[128 * 64];
  __shared__ __attribute__((aligned(16))) unsigned short Bs[128 * 64];
  const GemmDesc d = p.g[blockIdx.x >> 9];
  const int t = blockIdx.x & 511;
  const int bx = t & ((1 << d.nbx_shift) - 1);
  const int by = t >> d.nbx_shift;

  const int tid = threadIdx.x;
  const int lane = tid & 63, wave = tid >> 6;
  const int lr = lane & 15, lg = lane >> 4;
  const int rowBase = by * 128;
  const int colBase = bx * 128;
  const int wm = (wave & 1) * 64, wn = (wave >> 1) * 64;

  f32x4 acc[4][4] = {};

  // staging: 4 slots/thread/matrix; slot s -> row=s>>3, seg t=s&7,
  // global chunk c = t ^ (row&7)  (reader swizzle matches)
  const unsigned short* gA[4];
  const unsigned short* gB[4];
  unsigned short* lA[4];
  unsigned short* lB[4];
#pragma unroll
  for (int i = 0; i < 4; ++i) {
    int s = tid + i * 256;
    int row = s >> 3;
    int c = (s & 7) ^ (row & 7);
    gA[i] = d.A + (size_t)(rowBase + row) * 1024 + c * 8;
    gB[i] = d.Bt + (size_t)(colBase + row) * 1024 + c * 8;
    lA[i] = &As[s * 8];
    lB[i] = &Bs[s * 8];
  }

  for (int kt = 0; kt < 16; ++kt) {
    const int ko = kt * 64;
#pragma unroll
    for (int i = 0; i < 4; ++i) {
      gl2lds16(gA[i] + ko, lA[i]);
      gl2lds16(gB[i] + ko, lB[i]);
    }
    __syncthreads();  // drains vmcnt before barrier (m97 structure)

#pragma unroll
    for (int ks = 0; ks < 2; ++ks) {
      bf16x8 af[4], bfr[4];
#pragma unroll
      for (int mt = 0; mt < 4; ++mt) {
        int row = wm + mt * 16 + lr;
        int c = (ks * 4 + lg) ^ (row & 7);
        af[mt] = *(const bf16x8*)&As[row * 64 + c * 8];
      }
#pragma unroll
      for (int nt = 0; nt < 4; ++nt) {
        int row = wn + nt * 16 + lr;
        int c = (ks * 4 + lg) ^ (row & 7);
        bfr[nt] = *(const bf16x8*)&Bs[row * 64 + c * 8];
      }
#pragma unroll
      for (int mt = 0; mt < 4; ++mt)
#pragma unroll
        for (int nt = 0; nt < 4; ++nt)
          acc[mt][nt] = __builtin_amdgcn_mfma_f32_16x16x32_bf16(
              af[mt], bfr[nt], acc[mt][nt], 0, 0, 0);
    }
    __syncthreads();  // waves done reading before restage
  }

  // epilogue: C-layout col=lane&15, row=(lane>>4)*4+reg
#pragma unroll
  for (int mt = 0; mt < 4; ++mt)
#pragma unroll
    for (int nt = 0; nt < 4; ++nt) {
      int col = colBase + wn + nt * 16 + lr;
      int colStore = d.permc ? (colBase + wn + lr * 4 + nt) : col;
      float bcol = d.bias_row ? 0.f : d.bias[col];
#pragma unroll
      for (int r = 0; r < 4; ++r) {
        int row = rowBase + wm + mt * 16 + lg * 4 + r;
        float b = d.bias_row ? d.bias[row] : bcol;
        float val = (acc[mt][nt][r] + b) * d.scale;
        size_t idx = (size_t)row * (size_t)d.N + (size_t)colStore;
        if (OUT_F32)
          ((float*)d.C)[idx] = val;
        else
          ((unsigned short*)d.C)[idx] = f2bf(val);
      }
    }
}

// ---------------------------------------------------------------- attention
// One block per (n, h, 128-row q-tile).  4 waves x 32 q-rows.  KT=64.
// XCD-local placement: all 16 q-tiles of one (n,h) land on the SAME XCD
// (dispatch round-robins XCD = bid%8) -> K/V panels L2-resident.
// Swapped QK^T (zero-C first MFMA), in-register P via cvt_pk + permlane
// swaps, row-sum via ones-MFMA, K/V double-buffered, one barrier/kt,
// prefetch before compute, setprio(1) around MFMA clusters, kt unrolled
// 2x so LDS read addresses fold to 4 base pointers + immediate offsets.
__global__ __launch_bounds__(256, 4) void attn_k(
    const unsigned short* __restrict__ qb,   // [8192][1024]
    const unsigned short* __restrict__ kb,   // [8192][1024]
    const unsigned short* __restrict__ vtb,  // [1024][8192] natural key order
    unsigned short* __restrict__ aob) {      // [8192][1024]
  __shared__ __attribute__((aligned(16))) unsigned short Ks[2 * 64 * 64];
  __shared__ __attribute__((aligned(16))) unsigned short Vts[2 * 64 * 64];

  const int tid = threadIdx.x;
  const int lane = tid & 63, wave = tid >> 6;
  const int lr = lane & 15, lg = lane >> 4;

  // XCD-local swizzle: xcd = bid&7 (dispatch round-robin), 16 q-tiles of
  // each nh stay on one XCD.  Bijective: nh = (idx>>4)*8 + xcd in [0,64).
  const int bid = blockIdx.x;
  const int xcd = bid & 7;
  const int idx = bid >> 3;
  const int qt = idx & 15;
  const int nh = (idx >> 4) * 8 + xcd;
  const int h = nh & 15, n = nh >> 4;
  const int q0 = qt * 128;

  // ---- stage Q tile (128x64 = 16KB) overlaying both K buffers
#pragma unroll
  for (int i = 0; i < 4; ++i) {
    int s = i * 256 + tid;
    int row = s >> 3;
    int c = (s & 7) ^ (row & 7);
    gl2lds16(qb + (((size_t)n * 2048 + q0 + row) << 10) + h * 64 + c * 8,
             &Ks[s * 8]);
  }
  __syncthreads();

  bf16x8 aq[2][2];
#pragma unroll
  for (int mt = 0; mt < 2; ++mt)
#pragma unroll
    for (int ks = 0; ks < 2; ++ks) {
      int row = wave * 32 + mt * 16 + lr;
      int c = (ks * 4 + lg) ^ (row & 7);
      aq[mt][ks] = *(const bf16x8*)&Ks[row * 64 + c * 8];
    }
  __syncthreads();  // Q reads done; Ks becomes K double-buffer

  // per-lane LDS read bases: index = nt*1024 + lr*64 + c(ks)*8 (+cb)
  const int a0 = lr * 64 + ((lg ^ (lr & 7)) * 8);
  const int a1 = lr * 64 + (((4 + lg) ^ (lr & 7)) * 8);
  const unsigned short* Kb0 = &Ks[a0];
  const unsigned short* Kb1 = &Ks[a1];
  const unsigned short* Vb0 = &Vts[a0];
  const unsigned short* Vb1 = &Vts[a1];

  // staging addresses fixed per thread; advance by one tile per iteration
  const unsigned short* kg[2];
  const unsigned short* vg[2];
  int ldo[2];
#pragma unroll
  for (int i = 0; i < 2; ++i) {
    int s = i * 256 + tid;
    int row = s >> 3;
    int c = (s & 7) ^ (row & 7);
    kg[i] = kb + (((size_t)n * 2048 + row) << 10) + h * 64 + c * 8;
    vg[i] = vtb + (((size_t)(h * 64 + row)) << 13) + (size_t)n * 2048 + c * 8;
    ldo[i] = s * 8;
  }
  // stage k-tile 0 into buffer 0
#pragma unroll
  for (int i = 0; i < 2; ++i) {
    gl2lds16(kg[i], &Ks[ldo[i]]);
    gl2lds16(vg[i], &Vts[ldo[i]]);
    kg[i] += 64 * 1024;
    vg[i] += 64;
  }

  bf16x8 ones;
#pragma unroll
  for (int i = 0; i < 8; ++i) ones[i] = (__bf16)1.0f;
  const f32x4 fzero = {0.f, 0.f, 0.f, 0.f};

  f32x4 o_acc[2][4] = {};
  f32x4 o_sum[2] = {};

#pragma unroll 2
  for (int kt = 0; kt < 32; ++kt) {
    const int cb = (kt & 1) * 4096;  // current buffer base (shorts)
    const int nb = 4096 - cb;        // next buffer base
    __syncthreads();  // buf[cur] staged; prior reads of buf[next] complete

    if (kt < 31) {  // prefetch next tile before compute (loads overlap MFMA)
#pragma unroll
      for (int i = 0; i < 2; ++i) {
        gl2lds16(kg[i], &Ks[nb + ldo[i]]);
        gl2lds16(vg[i], &Vts[nb + ldo[i]]);
        kg[i] += 64 * 1024;
        vg[i] += 64;
      }
    }

    // swapped QK^T: s_acc[mt][nt] = S^T tile (row=key nt*16+lg*4+r, col=q)
    // zero-C: first MFMA takes fzero as C -> no per-kt accumulator clears.
    bf16x8 kf0[4], kf1[4];
#pragma unroll
    for (int nt = 0; nt < 4; ++nt) {
      kf0[nt] = *(const bf16x8*)(Kb0 + cb + nt * 1024);
      kf1[nt] = *(const bf16x8*)(Kb1 + cb + nt * 1024);
    }
    f32x4 s_acc[2][4];
    __builtin_amdgcn_s_setprio(1);
#pragma unroll
    for (int mt = 0; mt < 2; ++mt)
#pragma unroll
      for (int nt = 0; nt < 4; ++nt) {
        f32x4 t0 = __builtin_amdgcn_mfma_f32_16x16x32_bf16(
            kf0[nt], aq[mt][0], fzero, 0, 0, 0);
        s_acc[mt][nt] = __builtin_amdgcn_mfma_f32_16x16x32_bf16(
            kf1[nt], aq[mt][1], t0, 0, 0, 0);
      }
    __builtin_amdgcn_s_setprio(0);

    // no-max softmax + in-register P->A-fragment rearrangement.
    // lane (g'=lg, q=lr+mt*16) holds P^T[k=16nt+4g'+r][q].  PV A-frag needs
    // P[q][k=8g..8g+7] in lane group g (natural key order).
    bf16x8 ap[2][2];
#pragma unroll
    for (int mt = 0; mt < 2; ++mt) {
#pragma unroll
      for (int ks = 0; ks < 2; ++ks) {
        float pe[2][4];
#pragma unroll
        for (int half = 0; half < 2; ++half) {
          int nt = ks * 2 + half;
#pragma unroll
          for (int r = 0; r < 4; ++r)
            pe[half][r] = __builtin_amdgcn_exp2f(s_acc[mt][nt][r]);
        }
        unsigned int x00 = pk2(pe[0][0], pe[0][1]);
        unsigned int x01 = pk2(pe[0][2], pe[0][3]);
        unsigned int x10 = pk2(pe[1][0], pe[1][1]);
        unsigned int x11 = pk2(pe[1][2], pe[1][3]);
        uint2v s0 = __builtin_amdgcn_permlane32_swap(x00, x10, false, false);
        uint2v t0 = __builtin_amdgcn_permlane16_swap(s0[0], s0[1], false, false);
        uint2v s1 = __builtin_amdgcn_permlane32_swap(x01, x11, false, false);
        uint2v t1 = __builtin_amdgcn_permlane16_swap(s1[0], s1[1], false, false);
        uint4v u;
        u[0] = t0[0];  // k 8g+0,1
        u[1] = t1[0];  // k 8g+2,3
        u[2] = t0[1];  // k 8g+4,5
        u[3] = t1[1];  // k 8g+6,7
        ap[mt][ks] = __builtin_bit_cast(bf16x8, u);
      }
    }

    // PV + row-sum (ones-MFMA): O[q][d] += P*V;  o_sum = P*1
    bf16x8 bv0[4], bv1[4];
#pragma unroll
    for (int nt = 0; nt < 4; ++nt) {
      bv0[nt] = *(const bf16x8*)(Vb0 + cb + nt * 1024);
      bv1[nt] = *(const bf16x8*)(Vb1 + cb + nt * 1024);
    }
    __builtin_amdgcn_s_setprio(1);
#pragma unroll
    for (int mt = 0; mt < 2; ++mt) {
      o_sum[mt] = __builtin_amdgcn_mfma_f32_16x16x32_bf16(
          ap[mt][0], ones, o_sum[mt], 0, 0, 0);
      o_sum[mt] = __builtin_amdgcn_mfma_f32_16x16x32_bf16(
          ap[mt][1], ones, o_sum[mt], 0, 0, 0);
#pragma unroll
      for (int nt = 0; nt < 4; ++nt) {
        o_acc[mt][nt] = __builtin_amdgcn_mfma_f32_16x16x32_bf16(
            ap[mt][0], bv0[nt], o_acc[mt][nt], 0, 0, 0);
        o_acc[mt][nt] = __builtin_amdgcn_mfma_f32_16x16x32_bf16(
            ap[mt][1], bv1[nt], o_acc[mt][nt], 0, 0, 0);
      }
    }
    __builtin_amdgcn_s_setprio(0);
  }

  // epilogue: O C-layout col=d=lane&15, row=q=(lane>>4)*4+r.
  // o_sum[mt][r] is the full row-sum for this lane's O-row already.
#pragma unroll
  for (int mt = 0; mt < 2; ++mt) {
#pragma unroll
    for (int r = 0; r < 4; ++r) {
      float inv = 1.0f / o_sum[mt][r];
      int row_l = q0 + wave * 32 + mt * 16 + lg * 4 + r;
      size_t base = (((size_t)n * 2048 + row_l) << 10) + h * 64;
#pragma unroll
      for (int nt = 0; nt < 4; ++nt)
        aob[base + nt * 16 + lr] = f2bf(o_acc[mt][nt][r] * inv);
    }
  }
}

// ---------------------------------------------------------------- launch
extern "C" void kernel_launch(void* const* d_in, const int* in_sizes, int n_in,
                              void* d_out, int out_size, void* d_ws,
                              size_t ws_size, hipStream_t stream) {
  const float* Q = (const float*)d_in[0];
  const float* K = (const float*)d_in[1];
  const float* V = (const float*)d_in[2];
  const float* Wq = (const float*)d_in[3];
  const float* bq = (const float*)d_in[4];
  const float* Wk = (const float*)d_in[5];
  const float* bk = (const float*)d_in[6];
  const float* Wv = (const float*)d_in[7];
  const float* bv = (const float*)d_in[8];
  const float* Wo = (const float*)d_in[9];
  const float* bo = (const float*)d_in[10];

  const size_t S = (size_t)8192 * 1024;
  const size_t W = (size_t)1024 * 1024;
  unsigned short* ws = (unsigned short*)d_ws;
  unsigned short* Qbf = ws;  // dead after q-proj; reused as attention output
  unsigned short* Kbf = ws + S;
  unsigned short* Vbf = ws + 2 * S;
  unsigned short* qbuf = ws + 3 * S;
  unsigned short* kbuf = ws + 4 * S;
  unsigned short* vtbuf = ws + 5 * S;
  unsigned short* Wqb = ws + 6 * S;
  unsigned short* Wkb = Wqb + W;
  unsigned short* Wvb = Wqb + 2 * W;
  unsigned short* Wob = Wqb + 3 * W;
  unsigned short* aob = Qbf;

  CvtArgs cv;
  cv.src[0] = Q;  cv.dst[0] = Qbf;
  cv.src[1] = K;  cv.dst[1] = Kbf;
  cv.src[2] = V;  cv.dst[2] = Vbf;
  cv.src[3] = Wq; cv.dst[3] = Wqb;
  cv.src[4] = Wk; cv.dst[4] = Wkb;
  cv.src[5] = Wv; cv.dst[5] = Wvb;
  cv.src[6] = Wo; cv.dst[6] = Wob;
  cvt_all_k<<<28672, 256, 0, stream>>>(cv);

  // fused QKV projections: g0: q = (Qbf Wq^T + bq)*log2e/8  [8192x1024]
  //                        g1: k =  Kbf Wk^T + bk           [8192x1024]
  //                        g2: v^T = Wvb Vbf^T + bv (natural order) [1024x8192]
  GemmPack3 pp;
  pp.g[0] = {Qbf, Wqb, bq, qbuf, 1024, 3, LOG2E_OVER_SQRTD, 0, 0};
  pp.g[1] = {Kbf, Wkb, bk, kbuf, 1024, 3, 1.0f, 0, 0};
  pp.g[2] = {Wvb, Vbf, bv, vtbuf, 8192, 6, 1.0f, 1, 0};
  gemm_multi_k<false><<<1536, 256, 0, stream>>>(pp);

  attn_k<<<1024, 256, 0, stream>>>(qbuf, kbuf, vtbuf, aob);

  // out = AO Wo^T + bo  (fp32)
  GemmPack3 po;
  po.g[0] = {aob, Wob, bo, d_out, 1024, 3, 1.0f, 0, 0};
  po.g[1] = po.g[0];
  po.g[2] = po.g[0];
  gemm_multi_k<true><<<512, 256, 0, stream>>>(po);
}